// Round 5
// baseline (1881.599 us; speedup 1.0000x reference)
//
#include <hip/hip_runtime.h>
#include <hip/hip_bf16.h>

typedef __attribute__((ext_vector_type(4))) float f32x4;
typedef __attribute__((ext_vector_type(8))) short bf16x8;
typedef __attribute__((ext_vector_type(4))) short bf16x4v;

#define M_DIM 8192
#define N_DIM 4096
#define K_DIM 4096
#define NX (M_DIM * K_DIM)
#define NW (N_DIM * K_DIM)

#define BM 256
#define BN 256
#define BK 64
#define NKT (K_DIM / BK)   /* 64 */
#define THREADS 512

#define GLOAD_LDS16(g, l)                                                        \
  __builtin_amdgcn_global_load_lds(                                              \
      (const __attribute__((address_space(1))) void*)(g),                        \
      (__attribute__((address_space(3))) void*)(l), 16, 0, 0)

// ---------------------------------------------------------------------------
// Pass 1: fp32 -> bf16 conversion of x and W into workspace.
// ---------------------------------------------------------------------------
__global__ __launch_bounds__(256) void convert_bf16(const float* __restrict__ x,
                                                    const float* __restrict__ w,
                                                    short* __restrict__ ws) {
  const long stride = (long)gridDim.x * blockDim.x;
  const long total8 = ((long)NX + NW) / 8;
  for (long i = blockIdx.x * (long)blockDim.x + threadIdx.x; i < total8; i += stride) {
    const long base = i * 8;
    const float* src = (base < NX) ? (x + base) : (w + (base - NX));
    short* dst = ws + base;
    f32x4 a = *(const f32x4*)src;
    f32x4 b = *(const f32x4*)(src + 4);
    bf16x8 o;
    o[0] = (short)__bfloat16_as_ushort(__float2bfloat16(a[0]));
    o[1] = (short)__bfloat16_as_ushort(__float2bfloat16(a[1]));
    o[2] = (short)__bfloat16_as_ushort(__float2bfloat16(a[2]));
    o[3] = (short)__bfloat16_as_ushort(__float2bfloat16(a[3]));
    o[4] = (short)__bfloat16_as_ushort(__float2bfloat16(b[0]));
    o[5] = (short)__bfloat16_as_ushort(__float2bfloat16(b[1]));
    o[6] = (short)__bfloat16_as_ushort(__float2bfloat16(b[2]));
    o[7] = (short)__bfloat16_as_ushort(__float2bfloat16(b[3]));
    *(bf16x8*)dst = o;
  }
}

// ---------------------------------------------------------------------------
// Pass 2: 256x256 bf16 GEMM, BK=64, 8 waves (2M x 4N), double-buffered LDS,
// tile-level software pipeline: 2 barriers/tile, reads of tile T+1 overlap
// the MFMA of tile T, counted vmcnt(8), 8-slot XOR swizzle, XCD swizzle.
// Y = relu(X @ W^T + b)
//
// LDS per buffer (64 KiB): A rows 0-255 at [0,32KB), B rows 0-255 at
// [32KB,64KB); row-major 128 B rows, 8 slots of 16 B, phys = logical^(row&7).
//
// Pipeline invariants (race audit):
//  - frags(T) are read from buf[T&1] entirely during tile T-1; the end
//    barrier of T-1 (after each wave's lgkmcnt(0)) seals those reads.
//  - stage(T+2 -> buf[T&1]) issues at the TOP of tile T (after that seal).
//  - vmcnt(8) mid-tile-T waits for stage(T+1) (8 older loads), leaving
//    stage(T+2)'s 8 in flight; the following barrier publishes residence.
// ---------------------------------------------------------------------------
__global__ __launch_bounds__(THREADS, 2) void gemm256_bf16(
    const short* __restrict__ Abf,   /* [M][K] bf16 */
    const short* __restrict__ Bbf,   /* [N][K] bf16 */
    const float* __restrict__ bias,
    float* __restrict__ Y) {
  __shared__ short lds[2 * 32768];   /* 128 KiB */
  char* const ldsb = (char*)lds;

  const int tid  = threadIdx.x;
  const int lane = tid & 63;
  const int wave = tid >> 6;       // 0..7
  const int wm   = wave >> 2;      // 0..1  (M half)
  const int wn   = wave & 3;       // 0..3  (N quarter)

  // XCD-aware bijective swizzle: 512 wgs = 8 XCDs x 64.
  const int lin = blockIdx.x + blockIdx.y * (N_DIM / BN);   // gridDim.x = 16
  const int swz = (lin & 7) * 64 + (lin >> 3);
  const int bx = swz & 15;         // N tile
  const int by = swz >> 4;         // M tile
  const long rowA0 = (long)by * BM;
  const long rowB0 = (long)bx * BN;

  // staging lane geometry: one GLOAD issue = 512 thr x 16 B = 64 rows x 128 B.
  // LDS linear row = is*64 + wave*8 + (lane>>3); phys slot = lane&7;
  // source col chunk = phys ^ (row&7) (inverse swizzle, pre-applied).
  const int sg_col = (((lane & 7) ^ ((lane >> 3) & 7)) << 3);
  const int s_row  = wave * 8 + (lane >> 3);

  const short* gA = Abf + (rowA0 + s_row) * (long)K_DIM + sg_col;
  const short* gB = Bbf + (rowB0 + s_row) * (long)K_DIM + sg_col;

  // fragment-read per-lane byte offsets: row = frag*16 + (lane&15),
  // phys slot = kslot ^ (row&7) = kslot ^ (lane&7).
  const int offk0 = (lane & 15) * 128 + ((((lane >> 4)) ^ (lane & 7)) << 4);
  const int offk1 = (lane & 15) * 128 + (((4 + (lane >> 4)) ^ (lane & 7)) << 4);

#define STAGE_A(BOFF_, TT) do {                                                  \
    const short* g_ = gA + (long)(TT) * BK;                                      \
    _Pragma("unroll")                                                            \
    for (int is_ = 0; is_ < 4; ++is_)                                            \
      GLOAD_LDS16(g_ + (long)is_ * 64 * K_DIM,                                   \
                  ldsb + (BOFF_) + is_ * 8192 + wave * 1024);                    \
  } while (0)

#define STAGE_B(BOFF_, TT) do {                                                  \
    const short* g_ = gB + (long)(TT) * BK;                                      \
    _Pragma("unroll")                                                            \
    for (int is_ = 0; is_ < 4; ++is_)                                            \
      GLOAD_LDS16(g_ + (long)is_ * 64 * K_DIM,                                   \
                  ldsb + (BOFF_) + 32768 + is_ * 8192 + wave * 1024);            \
  } while (0)

// read the full fragment set of one tile (A: 8m x 2kk, B: 4n x 2kk)
#define READ_SET(DA, DB, BOFF_) do {                                             \
    const char* pa_ = ldsb + (BOFF_) + wm * 16384;                               \
    const char* pb_ = ldsb + (BOFF_) + 32768 + wn * 8192;                        \
    _Pragma("unroll")                                                            \
    for (int m_ = 0; m_ < 8; ++m_) {                                             \
      DA[m_][0] = *(const bf16x8*)(pa_ + m_ * 2048 + offk0);                     \
      DA[m_][1] = *(const bf16x8*)(pa_ + m_ * 2048 + offk1);                     \
    }                                                                            \
    _Pragma("unroll")                                                            \
    for (int n_ = 0; n_ < 4; ++n_) {                                             \
      DB[n_][0] = *(const bf16x8*)(pb_ + n_ * 2048 + offk0);                     \
      DB[n_][1] = *(const bf16x8*)(pb_ + n_ * 2048 + offk1);                     \
    }                                                                            \
  } while (0)

// 32 MFMA: all m x n in {NB, NB+1}
#define MFMA_HALF(SA, SB, NB) do {                                               \
    __builtin_amdgcn_s_setprio(1);                                               \
    _Pragma("unroll")                                                            \
    for (int kk_ = 0; kk_ < 2; ++kk_)                                            \
      _Pragma("unroll")                                                          \
      for (int m_ = 0; m_ < 8; ++m_)                                             \
        _Pragma("unroll")                                                        \
        for (int n_ = 0; n_ < 2; ++n_)                                           \
          acc[m_][(NB) + n_] = __builtin_amdgcn_mfma_f32_16x16x32_bf16(          \
              SA[m_][kk_], SB[(NB) + n_][kk_], acc[m_][(NB) + n_], 0, 0, 0);     \
    __builtin_amdgcn_s_setprio(0);                                               \
  } while (0)

// One K-tile. SA/SB = this tile's frags (already in regs); DA/DB = next
// tile's frags (read mid-tile). STOFF = buffer this tile stages T+2 into;
// RDOFF = buffer holding tile T+1.
#define TILE(SA, SB, DA, DB, STOFF, RDOFF, T, DO_ST, DO_RD, VM8) do {            \
    if (DO_ST) {                                                                 \
      STAGE_A(STOFF, (T) + 2);                                                   \
      STAGE_B(STOFF, (T) + 2);                                                   \
      __builtin_amdgcn_sched_barrier(0);                                         \
    }                                                                            \
    MFMA_HALF(SA, SB, 0);                                                        \
    if (VM8) asm volatile("s_waitcnt vmcnt(8)" ::: "memory");                    \
    else     asm volatile("s_waitcnt vmcnt(0)" ::: "memory");                    \
    asm volatile("s_barrier" ::: "memory");                                      \
    if (DO_RD) {                                                                 \
      READ_SET(DA, DB, RDOFF);                                                   \
      __builtin_amdgcn_sched_barrier(0);                                         \
    }                                                                            \
    MFMA_HALF(SA, SB, 2);                                                        \
    asm volatile("s_waitcnt lgkmcnt(0)" ::: "memory");                           \
    asm volatile("s_barrier" ::: "memory");                                      \
  } while (0)

  f32x4 acc[8][4];
#pragma unroll
  for (int i = 0; i < 8; ++i)
#pragma unroll
    for (int j = 0; j < 4; ++j) acc[i][j] = (f32x4)0.0f;

  bf16x8 aX[8][2], bX[4][2], aY[8][2], bY[4][2];

  // ---- prologue: stage tiles 0,1; read frags(0) into set X; seal buf0 ----
  STAGE_A(0, 0);
  STAGE_B(0, 0);
  STAGE_A(65536, 1);
  STAGE_B(65536, 1);
  asm volatile("s_waitcnt vmcnt(8)" ::: "memory");   // tile 0 resident
  asm volatile("s_barrier" ::: "memory");
  READ_SET(aX, bX, 0);
  __builtin_amdgcn_sched_barrier(0);
  asm volatile("s_waitcnt lgkmcnt(0)" ::: "memory");
  asm volatile("s_barrier" ::: "memory");            // buf0 reads sealed

  // ---- main loop: 2 tiles per iteration, tiles 0..61 ----
  for (int tp = 0; tp < NKT / 2 - 1; ++tp) {
    const int t0 = 2 * tp;
    TILE(aX, bX, aY, bY, /*ST*/ 0,     /*RD*/ 65536, t0,     1, 1, 1);
    TILE(aY, bY, aX, bX, /*ST*/ 65536, /*RD*/ 0,     t0 + 1, 1, 1, 1);
  }
  // ---- tail: tiles 62 (reads frags 63), 63 (pure compute) ----
  TILE(aX, bX, aY, bY, 0, 65536, NKT - 2, 0, 1, 0);
  TILE(aY, bY, aX, bX, 65536, 0, NKT - 1, 0, 0, 0);

#undef TILE
#undef MFMA_HALF
#undef READ_SET
#undef STAGE_B
#undef STAGE_A

  // ---- epilogue: bias + relu, fp32 stores ----
  const int c0 = lane & 15;
  const int r0 = (lane >> 4) * 4;
#pragma unroll
  for (int j = 0; j < 4; ++j) {
    const long gc = rowB0 + wn * 64 + j * 16 + c0;
    const float bv = bias[gc];
#pragma unroll
    for (int i = 0; i < 8; ++i) {
      const long gr0 = rowA0 + wm * 128 + i * 16 + r0;
#pragma unroll
      for (int r = 0; r < 4; ++r) {
        float v = acc[i][j][r] + bv;
        Y[(gr0 + r) * (long)N_DIM + gc] = fmaxf(v, 0.0f);
      }
    }
  }
}

// ---------------------------------------------------------------------------
// Fallback (only if ws too small): fp32 reg-staged 128^2 kernel.
// ---------------------------------------------------------------------------
#define FBM 128
#define FBK 32
#define FLDSS 40
__global__ __launch_bounds__(256) void fallback_gemm(
    const float* __restrict__ X, const float* __restrict__ W,
    const float* __restrict__ bias, float* __restrict__ Y) {
  __shared__ short As[FBM * FLDSS];
  __shared__ short Bs[FBM * FLDSS];
  const int tid = threadIdx.x, lane = tid & 63, wave = tid >> 6;
  const int wm = (wave >> 1) * 64, wn = (wave & 1) * 64;
  const long rowA0 = (long)blockIdx.y * FBM, rowB0 = (long)blockIdx.x * FBM;
  const int srow = tid >> 3, scol = (tid & 7) * 4;
  const float* Aptr = X + (rowA0 + srow) * (long)K_DIM + scol;
  const float* Bptr = W + (rowB0 + srow) * (long)K_DIM + scol;
  f32x4 ra[4], rb[4];
#pragma unroll
  for (int i = 0; i < 4; ++i) {
    ra[i] = *(const f32x4*)(Aptr + (long)i * 32 * K_DIM);
    rb[i] = *(const f32x4*)(Bptr + (long)i * 32 * K_DIM);
  }
  f32x4 acc[4][4];
#pragma unroll
  for (int i = 0; i < 4; ++i)
#pragma unroll
    for (int j = 0; j < 4; ++j) acc[i][j] = (f32x4)0.0f;
  for (int kt = 0; kt < K_DIM / FBK; ++kt) {
    __syncthreads();
#pragma unroll
    for (int i = 0; i < 4; ++i) {
      bf16x4v pa, pb;
#pragma unroll
      for (int j = 0; j < 4; ++j) {
        pa[j] = (short)__bfloat16_as_ushort(__float2bfloat16(ra[i][j]));
        pb[j] = (short)__bfloat16_as_ushort(__float2bfloat16(rb[i][j]));
      }
      *(bf16x4v*)&As[(i * 32 + srow) * FLDSS + scol] = pa;
      *(bf16x4v*)&Bs[(i * 32 + srow) * FLDSS + scol] = pb;
    }
    if (kt + 1 < K_DIM / FBK) {
      const float* An = Aptr + (kt + 1) * FBK;
      const float* Bn = Bptr + (kt + 1) * FBK;
#pragma unroll
      for (int i = 0; i < 4; ++i) {
        ra[i] = *(const f32x4*)(An + (long)i * 32 * K_DIM);
        rb[i] = *(const f32x4*)(Bn + (long)i * 32 * K_DIM);
      }
    }
    __syncthreads();
    bf16x8 af[4], bfr[4];
#pragma unroll
    for (int i = 0; i < 4; ++i) {
      af[i]  = *(const bf16x8*)&As[(wm + i * 16 + (lane & 15)) * FLDSS + (lane >> 4) * 8];
      bfr[i] = *(const bf16x8*)&Bs[(wn + i * 16 + (lane & 15)) * FLDSS + (lane >> 4) * 8];
    }
#pragma unroll
    for (int i = 0; i < 4; ++i)
#pragma unroll
      for (int j = 0; j < 4; ++j)
        acc[i][j] = __builtin_amdgcn_mfma_f32_16x16x32_bf16(af[i], bfr[j], acc[i][j], 0, 0, 0);
  }
  const int r0 = (lane >> 4) * 4, c0 = lane & 15;
#pragma unroll
  for (int j = 0; j < 4; ++j) {
    const long gc = rowB0 + wn + j * 16 + c0;
    const float bv = bias[gc];
#pragma unroll
    for (int i = 0; i < 4; ++i) {
      const long gr0 = rowA0 + wm + i * 16 + r0;
#pragma unroll
      for (int r = 0; r < 4; ++r) {
        float v = acc[i][j][r] + bv;
        Y[(gr0 + r) * (long)N_DIM + gc] = fmaxf(v, 0.0f);
      }
    }
  }
}

extern "C" void kernel_launch(void* const* d_in, const int* in_sizes, int n_in,
                              void* d_out, int out_size, void* d_ws, size_t ws_size,
                              hipStream_t stream) {
  const float* x = (const float*)d_in[0];
  const float* w = (const float*)d_in[1];
  const float* b = (const float*)d_in[2];
  float* y = (float*)d_out;

  const size_t need = (size_t)(NX + NW) * sizeof(short);
  if (ws_size >= need) {
    short* ws = (short*)d_ws;
    convert_bf16<<<2048, 256, 0, stream>>>(x, w, ws);
    dim3 grid(N_DIM / BN, M_DIM / BM);
    gemm256_bf16<<<grid, dim3(THREADS), 0, stream>>>(ws, ws + NX, b, y);
  } else {
    dim3 grid(N_DIM / FBM, M_DIM / FBM);
    fallback_gemm<<<grid, dim3(256), 0, stream>>>(x, w, b, y);
  }
}

// Round 6
// 315.272 us; speedup vs baseline: 5.9682x; 5.9682x over previous
//
#include <hip/hip_runtime.h>
#include <hip/hip_bf16.h>

typedef __attribute__((ext_vector_type(4))) float f32x4;
typedef __attribute__((ext_vector_type(8))) short bf16x8;
typedef __attribute__((ext_vector_type(4))) short bf16x4v;

#define M_DIM 8192
#define N_DIM 4096
#define K_DIM 4096
#define NX (M_DIM * K_DIM)
#define NW (N_DIM * K_DIM)

#define BM 256
#define BN 256
#define BK 64
#define NKT (K_DIM / BK)   /* 64 */
#define THREADS 512

#define GLOAD_LDS16(g, l)                                                        \
  __builtin_amdgcn_global_load_lds(                                              \
      (const __attribute__((address_space(1))) void*)(g),                        \
      (__attribute__((address_space(3))) void*)(l), 16, 0, 0)

// ---------------------------------------------------------------------------
// Pass 1: fp32 -> bf16 conversion of x and W into workspace.
// ---------------------------------------------------------------------------
__global__ __launch_bounds__(256) void convert_bf16(const float* __restrict__ x,
                                                    const float* __restrict__ w,
                                                    short* __restrict__ ws) {
  const long stride = (long)gridDim.x * blockDim.x;
  const long total8 = ((long)NX + NW) / 8;
  for (long i = blockIdx.x * (long)blockDim.x + threadIdx.x; i < total8; i += stride) {
    const long base = i * 8;
    const float* src = (base < NX) ? (x + base) : (w + (base - NX));
    short* dst = ws + base;
    f32x4 a = *(const f32x4*)src;
    f32x4 b = *(const f32x4*)(src + 4);
    bf16x8 o;
    o[0] = (short)__bfloat16_as_ushort(__float2bfloat16(a[0]));
    o[1] = (short)__bfloat16_as_ushort(__float2bfloat16(a[1]));
    o[2] = (short)__bfloat16_as_ushort(__float2bfloat16(a[2]));
    o[3] = (short)__bfloat16_as_ushort(__float2bfloat16(a[3]));
    o[4] = (short)__bfloat16_as_ushort(__float2bfloat16(b[0]));
    o[5] = (short)__bfloat16_as_ushort(__float2bfloat16(b[1]));
    o[6] = (short)__bfloat16_as_ushort(__float2bfloat16(b[2]));
    o[7] = (short)__bfloat16_as_ushort(__float2bfloat16(b[3]));
    *(bf16x8*)dst = o;
  }
}

// ---------------------------------------------------------------------------
// Pass 2: 256x256 bf16 GEMM, BK=64, 8 waves (2M x 4N), double-buffered LDS.
// kk-half software pipeline: ds_reads of the next K=32 half-step overlap the
// MFMA of the current one; 2 barriers/tile; counted vmcnt(8); XOR swizzle.
// In-flight fragments = 2 sets x (A8 + B4) x 4 VGPR = 96 VGPR (fits 256 cap
// with 128 acc regs; the round-5 full-tile double set = 192 spilled).
// Y = relu(X @ W^T + b)
//
// LDS per buffer (64 KiB): A rows 0-255 at [0,32KB), B rows 0-255 at
// [32KB,64KB); row-major 128 B rows, 8 slots of 16 B, phys = logical^(row&7).
//
// Race audit:
//  - reads of buf[T&1] (tile T): kk0 during tile T-1's H-odd, kk1 during
//    tile T's H-even; lgkmcnt(0)+barrier A at T's H-odd seals them.
//  - stage(T+2 -> buf[T&1]) issues after barrier A.
//  - vmcnt(8) waits stage(T+1) (8 older loads), leaves stage(T+2) in
//    flight; barrier B publishes residence before any (T+1,kk0) read.
// ---------------------------------------------------------------------------
__global__ __launch_bounds__(THREADS, 2) void gemm256_bf16(
    const short* __restrict__ Abf,   /* [M][K] bf16 */
    const short* __restrict__ Bbf,   /* [N][K] bf16 */
    const float* __restrict__ bias,
    float* __restrict__ Y) {
  __shared__ short lds[2 * 32768];   /* 128 KiB */
  char* const ldsb = (char*)lds;

  const int tid  = threadIdx.x;
  const int lane = tid & 63;
  const int wave = tid >> 6;       // 0..7
  const int wm   = wave >> 2;      // 0..1  (M half)
  const int wn   = wave & 3;       // 0..3  (N quarter)

  // XCD-aware bijective swizzle: 512 wgs = 8 XCDs x 64.
  const int lin = blockIdx.x + blockIdx.y * (N_DIM / BN);   // gridDim.x = 16
  const int swz = (lin & 7) * 64 + (lin >> 3);
  const int bx = swz & 15;         // N tile
  const int by = swz >> 4;         // M tile
  const long rowA0 = (long)by * BM;
  const long rowB0 = (long)bx * BN;

  // staging: one GLOAD issue = 512 thr x 16 B = 64 rows x 128 B.
  // LDS linear row = is*64 + wave*8 + (lane>>3); phys slot = lane&7;
  // source col chunk = phys ^ (row&7) (inverse swizzle, pre-applied).
  const int sg_col = (((lane & 7) ^ ((lane >> 3) & 7)) << 3);
  const int s_row  = wave * 8 + (lane >> 3);

  const short* gA = Abf + (rowA0 + s_row) * (long)K_DIM + sg_col;
  const short* gB = Bbf + (rowB0 + s_row) * (long)K_DIM + sg_col;

  // fragment-read per-lane byte offsets: row = frag*16 + (lane&15),
  // phys slot = kslot ^ (row&7) = kslot ^ (lane&7).
  const int offk0 = (lane & 15) * 128 + ((((lane >> 4)) ^ (lane & 7)) << 4);
  const int offk1 = (lane & 15) * 128 + (((4 + (lane >> 4)) ^ (lane & 7)) << 4);

#define STAGE_A(BOFF_, TT) do {                                                  \
    const short* g_ = gA + (long)(TT) * BK;                                      \
    _Pragma("unroll")                                                            \
    for (int is_ = 0; is_ < 4; ++is_)                                            \
      GLOAD_LDS16(g_ + (long)is_ * 64 * K_DIM,                                   \
                  ldsb + (BOFF_) + is_ * 8192 + wave * 1024);                    \
  } while (0)

#define STAGE_B(BOFF_, TT) do {                                                  \
    const short* g_ = gB + (long)(TT) * BK;                                      \
    _Pragma("unroll")                                                            \
    for (int is_ = 0; is_ < 4; ++is_)                                            \
      GLOAD_LDS16(g_ + (long)is_ * 64 * K_DIM,                                   \
                  ldsb + (BOFF_) + 32768 + is_ * 8192 + wave * 1024);            \
  } while (0)

// read one kk-half of a tile's fragments (A: 8 x b128, B: 4 x b128)
#define READ_KK(DA, DB, BOFF_, OFFK_) do {                                       \
    const char* pa_ = ldsb + (BOFF_) + wm * 16384;                               \
    const char* pb_ = ldsb + (BOFF_) + 32768 + wn * 8192;                        \
    _Pragma("unroll")                                                            \
    for (int m_ = 0; m_ < 8; ++m_)                                               \
      DA[m_] = *(const bf16x8*)(pa_ + m_ * 2048 + (OFFK_));                      \
    _Pragma("unroll")                                                            \
    for (int n_ = 0; n_ < 4; ++n_)                                               \
      DB[n_] = *(const bf16x8*)(pb_ + n_ * 2048 + (OFFK_));                      \
  } while (0)

// 32 MFMA: one kk-half, all 8m x 4n
#define MFMA_KK(SA, SB) do {                                                     \
    __builtin_amdgcn_s_setprio(1);                                               \
    _Pragma("unroll")                                                            \
    for (int m_ = 0; m_ < 8; ++m_)                                               \
      _Pragma("unroll")                                                          \
      for (int n_ = 0; n_ < 4; ++n_)                                             \
        acc[m_][n_] = __builtin_amdgcn_mfma_f32_16x16x32_bf16(                   \
            SA[m_], SB[n_], acc[m_][n_], 0, 0, 0);                               \
    __builtin_amdgcn_s_setprio(0);                                               \
  } while (0)

// One K-tile. Entry: a0/b0 hold (T,kk0); buf BUFT_ holds tile T.
// VMODE: 8 = steady (vmcnt(8)), 0 = drain (vmcnt(0)), -1 = none (last tile).
#define TILE(BUFT_, BUFN_, T, DO_ST, VMODE, DO_RD0) do {                         \
    /* H-even: read (T,kk1) -> set1; MFMA kk0 on set0 */                         \
    READ_KK(a1, b1, BUFT_, offk1);                                               \
    MFMA_KK(a0, b0);                                                             \
    /* H-odd */                                                                  \
    asm volatile("s_waitcnt lgkmcnt(0)" ::: "memory");                           \
    if ((VMODE) >= 0) {                                                          \
      __builtin_amdgcn_s_barrier();            /* A: seal buf reads */           \
      if (DO_ST) { STAGE_A(BUFT_, (T) + 2); STAGE_B(BUFT_, (T) + 2); }           \
      if ((VMODE) == 8) asm volatile("s_waitcnt vmcnt(8)" ::: "memory");         \
      else              asm volatile("s_waitcnt vmcnt(0)" ::: "memory");         \
      __builtin_amdgcn_s_barrier();            /* B: publish tile T+1 */         \
    }                                                                            \
    if (DO_RD0) READ_KK(a0, b0, BUFN_, offk0);                                   \
    MFMA_KK(a1, b1);                                                             \
  } while (0)

  f32x4 acc[8][4];
#pragma unroll
  for (int i = 0; i < 8; ++i)
#pragma unroll
    for (int j = 0; j < 4; ++j) acc[i][j] = (f32x4)0.0f;

  bf16x8 a0[8], b0[4], a1[8], b1[4];

  // ---- prologue: stage tiles 0,1; read (0,kk0) into set0 ----
  STAGE_A(0, 0);
  STAGE_B(0, 0);
  STAGE_A(65536, 1);
  STAGE_B(65536, 1);
  asm volatile("s_waitcnt vmcnt(8)" ::: "memory");   // tile 0 resident
  __builtin_amdgcn_s_barrier();
  READ_KK(a0, b0, 0, offk0);

  // ---- main loop: 2 tiles per iteration, tiles 0..61 ----
  for (int tp = 0; tp < NKT / 2 - 1; ++tp) {
    const int t0 = 2 * tp;
    TILE(0,     65536, t0,     1, 8, 1);
    TILE(65536, 0,     t0 + 1, 1, 8, 1);
  }
  // ---- tail: tile 62 (drain stage(63), read (63,kk0)), tile 63 ----
  TILE(0,     65536, NKT - 2, 0, 0, 1);
  TILE(65536, 0,     NKT - 1, 0, -1, 0);

#undef TILE
#undef MFMA_KK
#undef READ_KK
#undef STAGE_B
#undef STAGE_A

  // ---- epilogue: bias + relu, fp32 stores ----
  const int c0 = lane & 15;
  const int r0 = (lane >> 4) * 4;
#pragma unroll
  for (int j = 0; j < 4; ++j) {
    const long gc = rowB0 + wn * 64 + j * 16 + c0;
    const float bv = bias[gc];
#pragma unroll
    for (int i = 0; i < 8; ++i) {
      const long gr0 = rowA0 + wm * 128 + i * 16 + r0;
#pragma unroll
      for (int r = 0; r < 4; ++r) {
        float v = acc[i][j][r] + bv;
        Y[(gr0 + r) * (long)N_DIM + gc] = fmaxf(v, 0.0f);
      }
    }
  }
}

// ---------------------------------------------------------------------------
// Fallback (only if ws too small): fp32 reg-staged 128^2 kernel.
// ---------------------------------------------------------------------------
#define FBM 128
#define FBK 32
#define FLDSS 40
__global__ __launch_bounds__(256) void fallback_gemm(
    const float* __restrict__ X, const float* __restrict__ W,
    const float* __restrict__ bias, float* __restrict__ Y) {
  __shared__ short As[FBM * FLDSS];
  __shared__ short Bs[FBM * FLDSS];
  const int tid = threadIdx.x, lane = tid & 63, wave = tid >> 6;
  const int wm = (wave >> 1) * 64, wn = (wave & 1) * 64;
  const long rowA0 = (long)blockIdx.y * FBM, rowB0 = (long)blockIdx.x * FBM;
  const int srow = tid >> 3, scol = (tid & 7) * 4;
  const float* Aptr = X + (rowA0 + srow) * (long)K_DIM + scol;
  const float* Bptr = W + (rowB0 + srow) * (long)K_DIM + scol;
  f32x4 ra[4], rb[4];
#pragma unroll
  for (int i = 0; i < 4; ++i) {
    ra[i] = *(const f32x4*)(Aptr + (long)i * 32 * K_DIM);
    rb[i] = *(const f32x4*)(Bptr + (long)i * 32 * K_DIM);
  }
  f32x4 acc[4][4];
#pragma unroll
  for (int i = 0; i < 4; ++i)
#pragma unroll
    for (int j = 0; j < 4; ++j) acc[i][j] = (f32x4)0.0f;
  for (int kt = 0; kt < K_DIM / FBK; ++kt) {
    __syncthreads();
#pragma unroll
    for (int i = 0; i < 4; ++i) {
      bf16x4v pa, pb;
#pragma unroll
      for (int j = 0; j < 4; ++j) {
        pa[j] = (short)__bfloat16_as_ushort(__float2bfloat16(ra[i][j]));
        pb[j] = (short)__bfloat16_as_ushort(__float2bfloat16(rb[i][j]));
      }
      *(bf16x4v*)&As[(i * 32 + srow) * FLDSS + scol] = pa;
      *(bf16x4v*)&Bs[(i * 32 + srow) * FLDSS + scol] = pb;
    }
    if (kt + 1 < K_DIM / FBK) {
      const float* An = Aptr + (kt + 1) * FBK;
      const float* Bn = Bptr + (kt + 1) * FBK;
#pragma unroll
      for (int i = 0; i < 4; ++i) {
        ra[i] = *(const f32x4*)(An + (long)i * 32 * K_DIM);
        rb[i] = *(const f32x4*)(Bn + (long)i * 32 * K_DIM);
      }
    }
    __syncthreads();
    bf16x8 af[4], bfr[4];
#pragma unroll
    for (int i = 0; i < 4; ++i) {
      af[i]  = *(const bf16x8*)&As[(wm + i * 16 + (lane & 15)) * FLDSS + (lane >> 4) * 8];
      bfr[i] = *(const bf16x8*)&Bs[(wn + i * 16 + (lane & 15)) * FLDSS + (lane >> 4) * 8];
    }
#pragma unroll
    for (int i = 0; i < 4; ++i)
#pragma unroll
      for (int j = 0; j < 4; ++j)
        acc[i][j] = __builtin_amdgcn_mfma_f32_16x16x32_bf16(af[i], bfr[j], acc[i][j], 0, 0, 0);
  }
  const int r0 = (lane >> 4) * 4, c0 = lane & 15;
#pragma unroll
  for (int j = 0; j < 4; ++j) {
    const long gc = rowB0 + wn + j * 16 + c0;
    const float bv = bias[gc];
#pragma unroll
    for (int i = 0; i < 4; ++i) {
      const long gr0 = rowA0 + wm + i * 16 + r0;
#pragma unroll
      for (int r = 0; r < 4; ++r) {
        float v = acc[i][j][r] + bv;
        Y[(gr0 + r) * (long)N_DIM + gc] = fmaxf(v, 0.0f);
      }
    }
  }
}

extern "C" void kernel_launch(void* const* d_in, const int* in_sizes, int n_in,
                              void* d_out, int out_size, void* d_ws, size_t ws_size,
                              hipStream_t stream) {
  const float* x = (const float*)d_in[0];
  const float* w = (const float*)d_in[1];
  const float* b = (const float*)d_in[2];
  float* y = (float*)d_out;

  const size_t need = (size_t)(NX + NW) * sizeof(short);
  if (ws_size >= need) {
    short* ws = (short*)d_ws;
    convert_bf16<<<2048, 256, 0, stream>>>(x, w, ws);
    dim3 grid(N_DIM / BN, M_DIM / BM);
    gemm256_bf16<<<grid, dim3(THREADS), 0, stream>>>(ws, ws + NX, b, y);
  } else {
    dim3 grid(N_DIM / FBM, M_DIM / FBM);
    fallback_gemm<<<grid, dim3(256), 0, stream>>>(x, w, b, y);
  }
}

// Round 7
// 264.380 us; speedup vs baseline: 7.1170x; 1.1925x over previous
//
#include <hip/hip_runtime.h>
#include <hip/hip_bf16.h>

typedef __attribute__((ext_vector_type(4))) float f32x4;
typedef __attribute__((ext_vector_type(8))) short bf16x8;
typedef __attribute__((ext_vector_type(4))) short bf16x4v;

#define M_DIM 8192
#define N_DIM 4096
#define K_DIM 4096
#define NX (M_DIM * K_DIM)
#define NW (N_DIM * K_DIM)

#define BM 256
#define BN 256
#define BK 64
#define NKT (K_DIM / BK)   /* 64 */
#define THREADS 512

#define GLOAD_LDS16(g, l)                                                        \
  __builtin_amdgcn_global_load_lds(                                              \
      (const __attribute__((address_space(1))) void*)(g),                        \
      (__attribute__((address_space(3))) void*)(l), 16, 0, 0)

// ---------------------------------------------------------------------------
// Pass 1: fp32 -> bf16 conversion of x and W into workspace.
// ---------------------------------------------------------------------------
__global__ __launch_bounds__(256) void convert_bf16(const float* __restrict__ x,
                                                    const float* __restrict__ w,
                                                    short* __restrict__ ws) {
  const long stride = (long)gridDim.x * blockDim.x;
  const long total8 = ((long)NX + NW) / 8;
  for (long i = blockIdx.x * (long)blockDim.x + threadIdx.x; i < total8; i += stride) {
    const long base = i * 8;
    const float* src = (base < NX) ? (x + base) : (w + (base - NX));
    short* dst = ws + base;
    f32x4 a = *(const f32x4*)src;
    f32x4 b = *(const f32x4*)(src + 4);
    bf16x8 o;
    o[0] = (short)__bfloat16_as_ushort(__float2bfloat16(a[0]));
    o[1] = (short)__bfloat16_as_ushort(__float2bfloat16(a[1]));
    o[2] = (short)__bfloat16_as_ushort(__float2bfloat16(a[2]));
    o[3] = (short)__bfloat16_as_ushort(__float2bfloat16(a[3]));
    o[4] = (short)__bfloat16_as_ushort(__float2bfloat16(b[0]));
    o[5] = (short)__bfloat16_as_ushort(__float2bfloat16(b[1]));
    o[6] = (short)__bfloat16_as_ushort(__float2bfloat16(b[2]));
    o[7] = (short)__bfloat16_as_ushort(__float2bfloat16(b[3]));
    *(bf16x8*)dst = o;
  }
}

// ---------------------------------------------------------------------------
// Pass 2: 256x256 bf16 GEMM, BK=64, 8 waves (2M x 4N), double-buffered LDS,
// 4 phases per K-tile with ONE trailing barrier each; NO explicit lgkm
// drains (compiler emits fine-grained lgkmcnt); counted vmcnt(4); XOR
// swizzle; XCD swizzle; setprio.  Y = relu(X @ W^T + b)
//
// LDS per buffer (64 KiB): A rows 0-255 at [0,32KB) (half0 rows 0-127,
// half1 rows 128-255), B likewise at [32KB,64KB). Rows 128 B, 8 slots of
// 16 B, phys slot = logical ^ (row&7).
//
// Race audit (1 barrier/phase):
//  - every ds_read of phase p is consumed by an MFMA in phase p, so all a
//    wave's reads are complete before it reaches p's trailing barrier;
//  - stage(half X of t+2 -> buf[t&1]) at ph3 is ordered after ph2's
//    trailing barrier, by which point all reads of buf[t&1] are done;
//  - vmcnt(4)+barrier at ph3: waits t+1's hi-halves (4 older loads),
//    leaves t+2's lo-halves (4 newest) in flight; "memory" clobber
//    prevents hoisting next tile's ds_reads above it.
// ---------------------------------------------------------------------------
__global__ __launch_bounds__(THREADS, 2) void gemm256_bf16(
    const short* __restrict__ Abf,   /* [M][K] bf16 */
    const short* __restrict__ Bbf,   /* [N][K] bf16 */
    const float* __restrict__ bias,
    float* __restrict__ Y) {
  __shared__ short lds[2 * 32768];   /* 128 KiB */
  char* const ldsb = (char*)lds;

  const int tid  = threadIdx.x;
  const int lane = tid & 63;
  const int wave = tid >> 6;       // 0..7
  const int wm   = wave >> 2;      // 0..1  (M half)
  const int wn   = wave & 3;       // 0..3  (N quarter)

  // XCD-aware bijective swizzle: 512 wgs = 8 XCDs x 64.
  const int lin = blockIdx.x + blockIdx.y * (N_DIM / BN);   // gridDim.x = 16
  const int swz = (lin & 7) * 64 + (lin >> 3);
  const int bx = swz & 15;         // N tile
  const int by = swz >> 4;         // M tile
  const long rowA0 = (long)by * BM;
  const long rowB0 = (long)bx * BN;

  // staging: one GLOAD issue = 512 thr x 16 B = 64 rows x 128 B.
  // LDS linear row = wave*8 + (lane>>3) within a 64-row group; phys slot =
  // lane&7; source col chunk = phys ^ (row&7) (inverse swizzle).
  const int sg_col = (((lane & 7) ^ ((lane >> 3) & 7)) << 3);
  const int s_row  = wave * 8 + (lane >> 3);
  // per-lane 32-bit element offset within a 64-row panel (uniform base added
  // separately so the compiler can use the saddr global_load_lds form)
  const int voff = s_row * K_DIM + sg_col;

  // uniform panel bases (row offsets of each 64-row group)
  const short* uA = Abf + rowA0 * (long)K_DIM;
  const short* uB = Bbf + rowB0 * (long)K_DIM;

  // fragment-read per-lane byte offsets: row = frag*16 + (lane&15),
  // phys slot = kslot ^ (row&7) = kslot ^ (lane&7).
  const int offk0 = (lane & 15) * 128 + ((((lane >> 4)) ^ (lane & 7)) << 4);
  const int offk1 = (lane & 15) * 128 + (((4 + (lane >> 4)) ^ (lane & 7)) << 4);

// stage one half-tile (2 gloads). HALF: 0 = A rows 0-127, 1 = A rows 128-255,
// 2 = B rows 0-127, 3 = B rows 128-255.
#define STAGE_HALF(BOFF_, HALF_, TT) do {                                        \
    const short* u_ = ((HALF_) < 2 ? uA : uB) +                                  \
                      (long)(((HALF_) & 1) * 128) * K_DIM + (long)(TT) * BK;     \
    char* l_ = ldsb + (BOFF_) + ((HALF_) < 2 ? 0 : 32768) +                      \
               ((HALF_) & 1) * 16384 + wave * 1024;                              \
    GLOAD_LDS16(u_ + voff, l_);                                                  \
    GLOAD_LDS16(u_ + 64 * K_DIM + voff, l_ + 8192);                              \
  } while (0)

#define PH_READ_A(DST, BOFF_, MADD) do {                                         \
    const char* pa_ = ldsb + (BOFF_) + wm * 16384 + (MADD);                      \
    _Pragma("unroll")                                                            \
    for (int m_ = 0; m_ < 4; ++m_) {                                             \
      DST[m_][0] = *(const bf16x8*)(pa_ + m_ * 2048 + offk0);                    \
      DST[m_][1] = *(const bf16x8*)(pa_ + m_ * 2048 + offk1);                    \
    }                                                                            \
  } while (0)

#define PH_READ_B(DST, BOFF_, NADD) do {                                         \
    const char* pb_ = ldsb + (BOFF_) + 32768 + wn * 8192 + (NADD);               \
    _Pragma("unroll")                                                            \
    for (int n_ = 0; n_ < 2; ++n_) {                                             \
      DST[n_][0] = *(const bf16x8*)(pb_ + n_ * 2048 + offk0);                    \
      DST[n_][1] = *(const bf16x8*)(pb_ + n_ * 2048 + offk1);                    \
    }                                                                            \
  } while (0)

#define MFMA16(AF, BF, MB, NB) do {                                              \
    __builtin_amdgcn_s_setprio(1);                                               \
    _Pragma("unroll")                                                            \
    for (int kk_ = 0; kk_ < 2; ++kk_)                                            \
      _Pragma("unroll")                                                          \
      for (int m_ = 0; m_ < 4; ++m_)                                             \
        _Pragma("unroll")                                                        \
        for (int n_ = 0; n_ < 2; ++n_)                                           \
          acc[(MB) + m_][(NB) + n_] = __builtin_amdgcn_mfma_f32_16x16x32_bf16(   \
              AF[m_][kk_], BF[n_][kk_], acc[(MB) + m_][(NB) + n_], 0, 0, 0);     \
    __builtin_amdgcn_s_setprio(0);                                               \
  } while (0)

// One K-tile: 4 phases, one trailing barrier each. VM: 4 = steady vmcnt(4),
// 0 = drain vmcnt(0), -1 = none (last tile).
#define TILE(BOFF_, OOFF_, T, VM) do {                                           \
    /* ph0: read A m0-3 + B n0-1; stage A-hi(T+1); MFMA (m0-3, n0-1) */          \
    PH_READ_A(af, BOFF_, 0);                                                     \
    PH_READ_B(bfr01, BOFF_, 0);                                                  \
    if ((T) + 1 < NKT) STAGE_HALF(OOFF_, 1, (T) + 1);                            \
    MFMA16(af, bfr01, 0, 0);                                                     \
    __builtin_amdgcn_s_barrier();                                                \
    /* ph1: read B n2-3; stage B-hi(T+1); MFMA (m0-3, n2-3) */                   \
    PH_READ_B(bfr23, BOFF_, 4096);                                               \
    if ((T) + 1 < NKT) STAGE_HALF(OOFF_, 3, (T) + 1);                            \
    MFMA16(af, bfr23, 0, 2);                                                     \
    __builtin_amdgcn_s_barrier();                                                \
    /* ph2: read A m4-7; MFMA (m4-7, n0-1) */                                    \
    PH_READ_A(af, BOFF_, 8192);                                                  \
    MFMA16(af, bfr01, 4, 0);                                                     \
    __builtin_amdgcn_s_barrier();                                                \
    /* ph3: stage A-lo,B-lo(T+2); MFMA (m4-7, n2-3); counted vmcnt */            \
    if ((T) + 2 < NKT) { STAGE_HALF(BOFF_, 0, (T) + 2);                          \
                         STAGE_HALF(BOFF_, 2, (T) + 2); }                        \
    MFMA16(af, bfr23, 4, 2);                                                     \
    if ((VM) == 4)      asm volatile("s_waitcnt vmcnt(4)" ::: "memory");         \
    else if ((VM) == 0) asm volatile("s_waitcnt vmcnt(0)" ::: "memory");         \
    if ((VM) >= 0) __builtin_amdgcn_s_barrier();                                 \
  } while (0)

  f32x4 acc[8][4];
#pragma unroll
  for (int i = 0; i < 8; ++i)
#pragma unroll
    for (int j = 0; j < 4; ++j) acc[i][j] = (f32x4)0.0f;

  bf16x8 af[4][2], bfr01[2][2], bfr23[2][2];

  // ---- prologue: tile 0 fully; A-lo,B-lo of tile 1 ----
  STAGE_HALF(0, 0, 0);
  STAGE_HALF(0, 1, 0);
  STAGE_HALF(0, 2, 0);
  STAGE_HALF(0, 3, 0);
  STAGE_HALF(65536, 0, 1);
  STAGE_HALF(65536, 2, 1);
  asm volatile("s_waitcnt vmcnt(4)" ::: "memory");   // tile 0 resident
  __builtin_amdgcn_s_barrier();

  // ---- main loop: 2 tiles per iteration, tiles 0..61 ----
  for (int tp = 0; tp < NKT / 2 - 1; ++tp) {
    const int t0 = 2 * tp;
    TILE(0,     65536, t0,     4);
    TILE(65536, 0,     t0 + 1, 4);
  }
  // ---- tail: tile 62 (drain; stages 63's hi halves at ph0/ph1), tile 63 ----
  TILE(0,     65536, NKT - 2, 0);
  TILE(65536, 0,     NKT - 1, -1);

#undef TILE
#undef MFMA16
#undef PH_READ_B
#undef PH_READ_A
#undef STAGE_HALF

  // ---- epilogue: bias + relu, fp32 stores ----
  const int c0 = lane & 15;
  const int r0 = (lane >> 4) * 4;
#pragma unroll
  for (int j = 0; j < 4; ++j) {
    const long gc = rowB0 + wn * 64 + j * 16 + c0;
    const float bv = bias[gc];
#pragma unroll
    for (int i = 0; i < 8; ++i) {
      const long gr0 = rowA0 + wm * 128 + i * 16 + r0;
#pragma unroll
      for (int r = 0; r < 4; ++r) {
        float v = acc[i][j][r] + bv;
        Y[(gr0 + r) * (long)N_DIM + gc] = fmaxf(v, 0.0f);
      }
    }
  }
}

// ---------------------------------------------------------------------------
// Fallback (only if ws too small): fp32 reg-staged 128^2 kernel.
// ---------------------------------------------------------------------------
#define FBM 128
#define FBK 32
#define FLDSS 40
__global__ __launch_bounds__(256) void fallback_gemm(
    const float* __restrict__ X, const float* __restrict__ W,
    const float* __restrict__ bias, float* __restrict__ Y) {
  __shared__ short As[FBM * FLDSS];
  __shared__ short Bs[FBM * FLDSS];
  const int tid = threadIdx.x, lane = tid & 63, wave = tid >> 6;
  const int wm = (wave >> 1) * 64, wn = (wave & 1) * 64;
  const long rowA0 = (long)blockIdx.y * FBM, rowB0 = (long)blockIdx.x * FBM;
  const int srow = tid >> 3, scol = (tid & 7) * 4;
  const float* Aptr = X + (rowA0 + srow) * (long)K_DIM + scol;
  const float* Bptr = W + (rowB0 + srow) * (long)K_DIM + scol;
  f32x4 ra[4], rb[4];
#pragma unroll
  for (int i = 0; i < 4; ++i) {
    ra[i] = *(const f32x4*)(Aptr + (long)i * 32 * K_DIM);
    rb[i] = *(const f32x4*)(Bptr + (long)i * 32 * K_DIM);
  }
  f32x4 acc[4][4];
#pragma unroll
  for (int i = 0; i < 4; ++i)
#pragma unroll
    for (int j = 0; j < 4; ++j) acc[i][j] = (f32x4)0.0f;
  for (int kt = 0; kt < K_DIM / FBK; ++kt) {
    __syncthreads();
#pragma unroll
    for (int i = 0; i < 4; ++i) {
      bf16x4v pa, pb;
#pragma unroll
      for (int j = 0; j < 4; ++j) {
        pa[j] = (short)__bfloat16_as_ushort(__float2bfloat16(ra[i][j]));
        pb[j] = (short)__bfloat16_as_ushort(__float2bfloat16(rb[i][j]));
      }
      *(bf16x4v*)&As[(i * 32 + srow) * FLDSS + scol] = pa;
      *(bf16x4v*)&Bs[(i * 32 + srow) * FLDSS + scol] = pb;
    }
    if (kt + 1 < K_DIM / FBK) {
      const float* An = Aptr + (kt + 1) * FBK;
      const float* Bn = Bptr + (kt + 1) * FBK;
#pragma unroll
      for (int i = 0; i < 4; ++i) {
        ra[i] = *(const f32x4*)(An + (long)i * 32 * K_DIM);
        rb[i] = *(const f32x4*)(Bn + (long)i * 32 * K_DIM);
      }
    }
    __syncthreads();
    bf16x8 af[4], bfr[4];
#pragma unroll
    for (int i = 0; i < 4; ++i) {
      af[i]  = *(const bf16x8*)&As[(wm + i * 16 + (lane & 15)) * FLDSS + (lane >> 4) * 8];
      bfr[i] = *(const bf16x8*)&Bs[(wn + i * 16 + (lane & 15)) * FLDSS + (lane >> 4) * 8];
    }
#pragma unroll
    for (int i = 0; i < 4; ++i)
#pragma unroll
      for (int j = 0; j < 4; ++j)
        acc[i][j] = __builtin_amdgcn_mfma_f32_16x16x32_bf16(af[i], bfr[j], acc[i][j], 0, 0, 0);
  }
  const int r0 = (lane >> 4) * 4, c0 = lane & 15;
#pragma unroll
  for (int j = 0; j < 4; ++j) {
    const long gc = rowB0 + wn + j * 16 + c0;
    const float bv = bias[gc];
#pragma unroll
    for (int i = 0; i < 4; ++i) {
      const long gr0 = rowA0 + wm + i * 16 + r0;
#pragma unroll
      for (int r = 0; r < 4; ++r) {
        float v = acc[i][j][r] + bv;
        Y[(gr0 + r) * (long)N_DIM + gc] = fmaxf(v, 0.0f);
      }
    }
  }
}

extern "C" void kernel_launch(void* const* d_in, const int* in_sizes, int n_in,
                              void* d_out, int out_size, void* d_ws, size_t ws_size,
                              hipStream_t stream) {
  const float* x = (const float*)d_in[0];
  const float* w = (const float*)d_in[1];
  const float* b = (const float*)d_in[2];
  float* y = (float*)d_out;

  const size_t need = (size_t)(NX + NW) * sizeof(short);
  if (ws_size >= need) {
    short* ws = (short*)d_ws;
    convert_bf16<<<2048, 256, 0, stream>>>(x, w, ws);
    dim3 grid(N_DIM / BN, M_DIM / BM);
    gemm256_bf16<<<grid, dim3(THREADS), 0, stream>>>(ws, ws + NX, b, y);
  } else {
    dim3 grid(N_DIM / FBM, M_DIM / FBM);
    fallback_gemm<<<grid, dim3(256), 0, stream>>>(x, w, b, y);
  }
}